// Round 6
// baseline (68.523 us; speedup 1.0000x reference)
//
#include <hip/hip_runtime.h>
#include <hip/hip_bf16.h>
#include <math.h>

#define KCOMP 1024
#define DDIM  6
#define BPTS  16384

#define PTS    64            // points per block (4 MFMA pt-tiles of 16)
#define NWAVE  16            // waves per block; wave w owns comps [w*64, w*64+64)
#define NTPW   4             // n-tiles per wave (4 x 16 = 64 comps)

typedef __attribute__((ext_vector_type(8))) short bf16x8;  // 8 bf16 = 4 VGPRs
typedef __attribute__((ext_vector_type(4))) float f32x4;

// self-contained bf16 helpers (RNE)
__device__ __forceinline__ unsigned short f32_to_bf16(float f) {
    unsigned int u = __float_as_uint(f);
    u += 0x7fffu + ((u >> 16) & 1u);
    return (unsigned short)(u >> 16);
}
__device__ __forceinline__ float bf16_to_f32(unsigned short h) {
    return __uint_as_float(((unsigned int)h) << 16);
}

// ---------------------------------------------------------------------------
// SINGLE fused kernel. 256 blocks x 1024 threads (16 waves, 4 waves/SIMD,
// 1 block/CU — LDS 140 KB of gfx950's 160 KB).
//
// Phase 1 (per-wave, no cross-wave deps for W):
//   Wave w owns comps [w*64, w*64+64); lane L computes comp k = w*64+L:
//   6x6 Cholesky -> L^-1 -> P = Sigma^-1, folds weights/logdet/mu into 32
//   log2-domain coefs (structure verified R4/R5, absmax 0.0625):
//     wv[0..20]  = log2e * (-0.5*P_ii / -P_ij)   (Z: x_i x_j, i<=j)
//     wv[21..26] = log2e * (P mu)_i              (Z: x_i)
//     wv[27]     = log2(w) - 0.5(6 log2(2pi) + log2det) - 0.5 log2e mu'Pmu
//     wv[28..31] = 0
//   then split-bf16 (hi + lo) and write into the wave's private LDS chunk in
//   MFMA B-fragment order (wave-internal transpose: lane-owns-comp ->
//   feature-major). Sigma >= 0.1 I bounds v2 above (~2): fixed-scale exp2
//   sums cannot overflow; all-comp underflow needs best < -87 nats.
//   Meanwhile waves 0..7 also build the shared A-fragments (split*4+pt) into
//   fragA (dedup: built once per block, consumed by all 16 waves).
//
// One __syncthreads(), then phase 2:
//   4 n-tiles x 4 pt-tiles x 3 mfma_f32_16x16x32_bf16 (split-bf16:
//   AhBh + AlBh + AhBl, dropping lo*lo ~2^-34), exp2 on the 4 C-regs,
//   accumulate, xor-butterfly over the 16 comp-lanes, LDS combine over waves.
//   A layout: lane=(quad<<4)|m holds Z[m][quad*8+j].
//   B layout: lane=(kq<<4)|n15 holds W[kq*8+j][n]; frag elem index for comp n,
//   feature k: ((n>>4)*64 + ((k>>3)<<4) + (n&15))*8 + (k&7).
//   C/D: col(comp)=lane&15, row(point)=quad*4+reg.
//
// Fuses away the former 16-block precompute kernel: saves one launch +
// inter-kernel drain (~2-4 us) at the cost of ~0.35 us per-wave redundant
// precompute. d_ws is no longer used.
// ---------------------------------------------------------------------------
__global__ __launch_bounds__(1024, 4) void gmm_fused(
        const float* __restrict__ x,
        const float* __restrict__ means,
        const float* __restrict__ covs,
        const float* __restrict__ weights,
        float* __restrict__ out) {
    const int tid  = threadIdx.x;
    const int lane = tid & 63;
    const int w    = __builtin_amdgcn_readfirstlane(tid >> 6);  // 0..15
    const int quad = lane >> 4;                                  // 0..3
    const int m15  = lane & 15;
    const int pbase = blockIdx.x * PTS;

    __shared__ short  WH[NWAVE * NTPW * 64 * 8];   // 64 KB, B-frag order (hi)
    __shared__ short  WL[NWAVE * NTPW * 64 * 8];   // 64 KB, B-frag order (lo)
    __shared__ bf16x8 fragA[8][64];                // 8 KB  [split*4+pt][lane]
    __shared__ float  partial[NWAVE][PTS];         // 4 KB

    // ---- phase 1a: producer waves build the shared A-fragments ----
    if (w < 8) {
        const int pt    = w & 3;
        const int split = w >> 2;            // 0 = hi, 1 = lo
        float v[6];
        const float* xp = x + (pbase + pt * 16 + m15) * 6;
        #pragma unroll
        for (int i = 0; i < 6; i++) v[i] = xp[i];

        float f[8];
        if (quad == 0) {
            f[0]=v[0]*v[0]; f[1]=v[0]*v[1]; f[2]=v[0]*v[2]; f[3]=v[0]*v[3];
            f[4]=v[0]*v[4]; f[5]=v[0]*v[5]; f[6]=v[1]*v[1]; f[7]=v[1]*v[2];
        } else if (quad == 1) {
            f[0]=v[1]*v[3]; f[1]=v[1]*v[4]; f[2]=v[1]*v[5]; f[3]=v[2]*v[2];
            f[4]=v[2]*v[3]; f[5]=v[2]*v[4]; f[6]=v[2]*v[5]; f[7]=v[3]*v[3];
        } else if (quad == 2) {
            f[0]=v[3]*v[4]; f[1]=v[3]*v[5]; f[2]=v[4]*v[4]; f[3]=v[4]*v[5];
            f[4]=v[5]*v[5]; f[5]=v[0];      f[6]=v[1];      f[7]=v[2];
        } else {
            f[0]=v[3]; f[1]=v[4]; f[2]=v[5]; f[3]=1.0f;
            f[4]=0.0f; f[5]=0.0f; f[6]=0.0f; f[7]=0.0f;
        }

        bf16x8 frag;
        #pragma unroll
        for (int j = 0; j < 8; j++) {
            unsigned short h = f32_to_bf16(f[j]);
            frag[j] = (split == 0) ? (short)h
                                   : (short)f32_to_bf16(f[j] - bf16_to_f32(h));
        }
        fragA[w][lane] = frag;
    }

    // ---- phase 1b: per-wave component precompute (comp k = w*64 + lane) ----
    {
        const int k = w * 64 + lane;

        float A[6][6];
        const float* C = covs + k * 36;
        #pragma unroll
        for (int i = 0; i < 6; i++)
            #pragma unroll
            for (int j = 0; j < 6; j++)
                A[i][j] = C[i * 6 + j];

        // In-place Cholesky (lower tri of A -> L); track diag product.
        float dprod = 1.0f;
        #pragma unroll
        for (int j = 0; j < 6; j++) {
            float d = A[j][j];
            #pragma unroll
            for (int t = 0; t < 6; t++) if (t < j) d -= A[j][t] * A[j][t];
            float ljj = __builtin_amdgcn_sqrtf(d);
            dprod *= ljj;
            A[j][j] = ljj;
            float inv = __builtin_amdgcn_rcpf(ljj);
            #pragma unroll
            for (int i = 0; i < 6; i++) {
                if (i > j) {
                    float s = A[i][j];
                    #pragma unroll
                    for (int t = 0; t < 6; t++) if (t < j) s -= A[i][t] * A[j][t];
                    A[i][j] = s * inv;
                }
            }
        }
        float logdet2 = 2.0f * __builtin_amdgcn_logf(dprod);   // log2(det)

        // Li = L^{-1} (lower)
        float Li[6][6];
        #pragma unroll
        for (int j = 0; j < 6; j++) {
            Li[j][j] = __builtin_amdgcn_rcpf(A[j][j]);
            #pragma unroll
            for (int i = 0; i < 6; i++) {
                if (i > j) {
                    float s = 0.0f;
                    #pragma unroll
                    for (int t = 0; t < 6; t++) if (t >= j && t < i) s += A[i][t] * Li[t][j];
                    Li[i][j] = -s * __builtin_amdgcn_rcpf(A[i][i]);
                }
            }
        }

        // P = Li^T Li -> overwrite A
        #pragma unroll
        for (int i = 0; i < 6; i++) {
            #pragma unroll
            for (int j = 0; j < 6; j++) {
                if (j >= i) {
                    float s = 0.0f;
                    int lo = (i > j) ? i : j;
                    #pragma unroll
                    for (int t = 0; t < 6; t++) if (t >= lo) s += Li[t][i] * Li[t][j];
                    A[i][j] = s;
                    A[j][i] = s;
                }
            }
        }

        const float* mu = means + k * 6;
        float m[6];
        #pragma unroll
        for (int i = 0; i < 6; i++) m[i] = mu[i];

        float b[6];
        float muPmu = 0.0f;
        #pragma unroll
        for (int i = 0; i < 6; i++) {
            float s = 0.0f;
            #pragma unroll
            for (int j = 0; j < 6; j++) s += A[i][j] * m[j];
            b[i] = s;
            muPmu += s * m[i];
        }

        const float LOG2_2PI = 2.6514961294723187f;   // log2(2*pi)
        const float LOG2E    = 1.4426950408889634f;
        float c2 = __builtin_amdgcn_logf(weights[k])
                 - 0.5f * (6.0f * LOG2_2PI + logdet2)
                 - 0.5f * LOG2E * muPmu;

        float wv[32];
        int t = 0;
        #pragma unroll
        for (int i = 0; i < 6; i++)
            #pragma unroll
            for (int j = 0; j < 6; j++)
                if (j >= i) wv[t++] = LOG2E * ((i == j) ? -0.5f * A[i][j] : -A[i][j]);
        #pragma unroll
        for (int i = 0; i < 6; i++) wv[t++] = LOG2E * b[i];
        wv[27] = c2;
        wv[28] = 0.0f; wv[29] = 0.0f; wv[30] = 0.0f; wv[31] = 0.0f;

        // Split-bf16 + wave-internal transpose into B-frag order.
        // comp k = w*64 + (tt*16 + n15), tt = lane>>4; frag elem index
        // (in bf16x8 units) = (w*4 + tt)*64 + kq*16 + n15.
        const int tt   = lane >> 4;
        const int base = (w * 4 + tt) * 64 + (lane & 15);
        bf16x8* wh8 = (bf16x8*)WH;
        bf16x8* wl8 = (bf16x8*)WL;
        #pragma unroll
        for (int kq = 0; kq < 4; kq++) {
            bf16x8 ph, pl;
            #pragma unroll
            for (int j = 0; j < 8; j++) {
                float v = wv[kq * 8 + j];
                unsigned short h = f32_to_bf16(v);
                ph[j] = (short)h;
                pl[j] = (short)f32_to_bf16(v - bf16_to_f32(h));
            }
            wh8[base + kq * 16] = ph;
            wl8[base + kq * 16] = pl;
        }
    }

    __syncthreads();

    // ---- phase 2: MFMA loop over this wave's 4 n-tiles ----
    bf16x8 Ah[4], Al[4];
    #pragma unroll
    for (int pt = 0; pt < 4; pt++) {
        Ah[pt] = fragA[pt][lane];
        Al[pt] = fragA[4 + pt][lane];
    }

    const bf16x8* wh8 = (const bf16x8*)WH + (w * NTPW) * 64;
    const bf16x8* wl8 = (const bf16x8*)WL + (w * NTPW) * 64;

    float esum[4][4];
    #pragma unroll
    for (int pt = 0; pt < 4; pt++)
        #pragma unroll
        for (int r = 0; r < 4; r++) esum[pt][r] = 0.0f;

    #pragma unroll
    for (int t = 0; t < NTPW; t++) {
        bf16x8 bh = wh8[t * 64 + lane];
        bf16x8 bl = wl8[t * 64 + lane];
        #pragma unroll
        for (int pt = 0; pt < 4; pt++) {
            f32x4 c = {0.0f, 0.0f, 0.0f, 0.0f};
            c = __builtin_amdgcn_mfma_f32_16x16x32_bf16(Ah[pt], bh, c, 0, 0, 0);
            c = __builtin_amdgcn_mfma_f32_16x16x32_bf16(Al[pt], bh, c, 0, 0, 0);
            c = __builtin_amdgcn_mfma_f32_16x16x32_bf16(Ah[pt], bl, c, 0, 0, 0);
            #pragma unroll
            for (int r = 0; r < 4; r++)
                esum[pt][r] += __builtin_amdgcn_exp2f(c[r]);
        }
    }

    // ---- reduce over the 16 comp-lanes (xor butterfly within 16-group) ----
    #pragma unroll
    for (int pt = 0; pt < 4; pt++) {
        #pragma unroll
        for (int r = 0; r < 4; r++) {
            float v = esum[pt][r];
            v += __shfl_xor(v, 1);
            v += __shfl_xor(v, 2);
            v += __shfl_xor(v, 4);
            v += __shfl_xor(v, 8);
            esum[pt][r] = v;
        }
    }

    if (m15 == 0) {
        #pragma unroll
        for (int pt = 0; pt < 4; pt++)
            #pragma unroll
            for (int r = 0; r < 4; r++)
                partial[w][pt * 16 + quad * 4 + r] = esum[pt][r];
    }
    __syncthreads();

    if (tid < PTS) {
        float S = 0.0f;
        #pragma unroll
        for (int c = 0; c < NWAVE; c++) S += partial[c][tid];
        const float LN2 = 0.6931471805599453f;
        out[pbase + tid] = LN2 * __builtin_amdgcn_logf(S);  // v_log_f32 = log2
    }
}

extern "C" void kernel_launch(void* const* d_in, const int* in_sizes, int n_in,
                              void* d_out, int out_size, void* d_ws, size_t ws_size,
                              hipStream_t stream) {
    const float* x       = (const float*)d_in[0];  // [B, 6]
    const float* means   = (const float*)d_in[1];  // [K, 6]
    const float* covs    = (const float*)d_in[2];  // [K, 6, 6]
    const float* weights = (const float*)d_in[3];  // [K]
    float* out = (float*)d_out;                    // [B]
    (void)d_ws; (void)ws_size;                     // workspace no longer needed

    gmm_fused<<<BPTS / PTS, 1024, 0, stream>>>(x, means, covs, weights, out);
}

// Round 7
// 66.103 us; speedup vs baseline: 1.0366x; 1.0366x over previous
//
#include <hip/hip_runtime.h>
#include <hip/hip_bf16.h>
#include <math.h>

#define KCOMP 1024
#define DDIM  6
#define BPTS  16384

#define PTS    64            // points per block (4 MFMA pt-tiles of 16)
#define NWAVE  16            // waves per block; wave w owns comps [w*64, w*64+64)
#define NTPW   4             // n-tiles per wave (4 x 16 = 64 comps)

typedef __attribute__((ext_vector_type(8))) short bf16x8;  // 8 bf16 = 4 VGPRs
typedef __attribute__((ext_vector_type(4))) float f32x4;

// self-contained bf16 helpers (RNE)
__device__ __forceinline__ unsigned short f32_to_bf16(float f) {
    unsigned int u = __float_as_uint(f);
    u += 0x7fffu + ((u >> 16) & 1u);
    return (unsigned short)(u >> 16);
}
__device__ __forceinline__ float bf16_to_f32(unsigned short h) {
    return __uint_as_float(((unsigned int)h) << 16);
}

// Sum across each row of 16 lanes via DPP rotate-adds (VALU pipe, ~2 cyc/op,
// vs ds_bpermute shuffle butterfly on the DS pipe ~8 cyc/op). After 4 steps
// every lane in the 16-group holds the full row sum.
__device__ __forceinline__ float row16_sum(float v) {
    int t;
    t = __builtin_amdgcn_update_dpp(0, __float_as_int(v), 0x121, 0xf, 0xf, false); // row_ror:1
    v += __int_as_float(t);
    t = __builtin_amdgcn_update_dpp(0, __float_as_int(v), 0x122, 0xf, 0xf, false); // row_ror:2
    v += __int_as_float(t);
    t = __builtin_amdgcn_update_dpp(0, __float_as_int(v), 0x124, 0xf, 0xf, false); // row_ror:4
    v += __int_as_float(t);
    t = __builtin_amdgcn_update_dpp(0, __float_as_int(v), 0x128, 0xf, 0xf, false); // row_ror:8
    v += __int_as_float(t);
    return v;
}

// ---------------------------------------------------------------------------
// Kernel 1: per-component precompute -> split-bf16 W matrix in MFMA B-operand
// fragment order. LOG2 domain. (R5 structure — separate kernel keeps the
// Cholesky's ~72 live floats out of the main kernel's VGPR budget; fusing it
// in-block regressed, R6.)
//   W[0..20,k]  = log2e * (-0.5*P_ii diag / -P_ij offdiag)   (Z: x_i x_j, i<=j)
//   W[21..26,k] = log2e * (P mu)_i                            (Z: x_i)
//   W[27,k]     = log2(w) - 0.5*(6*log2(2pi) + logdet2) - 0.5*log2e*mu^T P mu
//   W[28..31,k] = 0
// P = Sigma^{-1}. Sigma >= 0.1 I => v2 bounded above (~2): fixed-scale exp2
// sums cannot overflow; all-comp underflow needs best < -87 nats (unreachable).
// Fast-math: v_sqrt/v_rcp/v_log (1-ulp) — error far below the bf16-split term.
// Fragment order (16x16x32 B-operand: lane=(kq<<4)|n15 holds B[kq*8+j][n]):
//   idx(n,k) = ((n>>4)*64 + ((k>>3)<<4) + (n&15))*8 + (k&7)
// ---------------------------------------------------------------------------
__global__ __launch_bounds__(64, 1) void gmm_precompute(
        const float* __restrict__ means,
        const float* __restrict__ covs,
        const float* __restrict__ weights,
        unsigned short* __restrict__ Wh,     // [32768]
        unsigned short* __restrict__ Wl) {   // [32768]
    int k = blockIdx.x * 64 + threadIdx.x;
    if (k >= KCOMP) return;

    float A[6][6];
    const float* C = covs + k * 36;
    #pragma unroll
    for (int i = 0; i < 6; i++)
        #pragma unroll
        for (int j = 0; j < 6; j++)
            A[i][j] = C[i * 6 + j];

    // In-place Cholesky: lower triangle of A becomes L. Track diag product.
    float dprod = 1.0f;
    #pragma unroll
    for (int j = 0; j < 6; j++) {
        float d = A[j][j];
        #pragma unroll
        for (int t = 0; t < 6; t++) if (t < j) d -= A[j][t] * A[j][t];
        float ljj = __builtin_amdgcn_sqrtf(d);
        dprod *= ljj;
        A[j][j] = ljj;
        float inv = __builtin_amdgcn_rcpf(ljj);
        #pragma unroll
        for (int i = 0; i < 6; i++) {
            if (i > j) {
                float s = A[i][j];
                #pragma unroll
                for (int t = 0; t < 6; t++) if (t < j) s -= A[i][t] * A[j][t];
                A[i][j] = s * inv;
            }
        }
    }
    float logdet2 = 2.0f * __builtin_amdgcn_logf(dprod);   // log2(det Sigma)

    // Li = L^{-1} (lower)
    float Li[6][6];
    #pragma unroll
    for (int j = 0; j < 6; j++) {
        Li[j][j] = __builtin_amdgcn_rcpf(A[j][j]);
        #pragma unroll
        for (int i = 0; i < 6; i++) {
            if (i > j) {
                float s = 0.0f;
                #pragma unroll
                for (int t = 0; t < 6; t++) if (t >= j && t < i) s += A[i][t] * Li[t][j];
                Li[i][j] = -s * __builtin_amdgcn_rcpf(A[i][i]);
            }
        }
    }

    // P = Li^T Li -> overwrite A
    #pragma unroll
    for (int i = 0; i < 6; i++) {
        #pragma unroll
        for (int j = 0; j < 6; j++) {
            if (j >= i) {
                float s = 0.0f;
                int lo = (i > j) ? i : j;
                #pragma unroll
                for (int t = 0; t < 6; t++) if (t >= lo) s += Li[t][i] * Li[t][j];
                A[i][j] = s;
                A[j][i] = s;
            }
        }
    }

    const float* mu = means + k * 6;
    float m[6];
    #pragma unroll
    for (int i = 0; i < 6; i++) m[i] = mu[i];

    float b[6];
    float muPmu = 0.0f;
    #pragma unroll
    for (int i = 0; i < 6; i++) {
        float s = 0.0f;
        #pragma unroll
        for (int j = 0; j < 6; j++) s += A[i][j] * m[j];
        b[i] = s;
        muPmu += s * m[i];
    }

    const float LOG2_2PI = 2.6514961294723187f;   // log2(2*pi)
    const float LOG2E    = 1.4426950408889634f;
    float c2 = __builtin_amdgcn_logf(weights[k])
             - 0.5f * (6.0f * LOG2_2PI + logdet2)
             - 0.5f * LOG2E * muPmu;

    float wv[32];
    int t = 0;
    #pragma unroll
    for (int i = 0; i < 6; i++)
        #pragma unroll
        for (int j = 0; j < 6; j++)
            if (j >= i) wv[t++] = LOG2E * ((i == j) ? -0.5f * A[i][j] : -A[i][j]);
    #pragma unroll
    for (int i = 0; i < 6; i++) wv[t++] = LOG2E * b[i];
    wv[27] = c2;
    wv[28] = 0.0f; wv[29] = 0.0f; wv[30] = 0.0f; wv[31] = 0.0f;

    int ntile = k >> 4, n15 = k & 15;
    #pragma unroll
    for (int kk = 0; kk < 32; kk++) {
        float v = wv[kk];
        unsigned short h = f32_to_bf16(v);
        unsigned short l = f32_to_bf16(v - bf16_to_f32(h));
        int idx = ((ntile * 64) + ((kk >> 3) << 4) + n15) * 8 + (kk & 7);
        Wh[idx] = h;
        Wl[idx] = l;
    }
}

// ---------------------------------------------------------------------------
// Kernel 2: MFMA main. 256 blocks x 1024 threads (16 waves, 4 waves/SIMD).
// Block: 64 points (4 pt-tiles). Wave w: comps [w*64, w*64+64) (4 n-tiles).
// A-fragment build de-duplicated via 8 producer waves -> LDS (R5).
// Per (pt,n) tile: 3x mfma_f32_16x16x32_bf16 (split-bf16: AhBh+AlBh+AhBl),
// exp2 on 4 C-regs, accumulate; DPP row_ror reduce over the 16 comp-lanes
// (VALU pipe — replaces the ds_bpermute butterfly); LDS combine over waves.
// A layout: lane=(quad<<4)|m holds Z[m][quad*8+j].
// C/D layout: col(comp)=lane&15, row(point)=quad*4+reg.
// ---------------------------------------------------------------------------
__global__ __launch_bounds__(1024, 4) void gmm_main(
        const float* __restrict__ x,
        const unsigned short* __restrict__ Wh,
        const unsigned short* __restrict__ Wl,
        float* __restrict__ out) {
    const int tid  = threadIdx.x;
    const int lane = tid & 63;
    const int w    = __builtin_amdgcn_readfirstlane(tid >> 6);  // 0..15
    const int quad = lane >> 4;                                  // 0..3
    const int m15  = lane & 15;
    const int pbase = blockIdx.x * PTS;

    __shared__ bf16x8 fragA[8][64];          // [split*4+pt][lane], 8 KB
    __shared__ float  partial[NWAVE][PTS];   // 4 KB

    // ---- producer waves: build one (pt, split) fragment set ----
    if (w < 8) {
        const int pt    = w & 3;
        const int split = w >> 2;            // 0 = hi, 1 = lo
        float v[6];
        const float* xp = x + (pbase + pt * 16 + m15) * 6;
        #pragma unroll
        for (int i = 0; i < 6; i++) v[i] = xp[i];

        float f[8];
        if (quad == 0) {
            f[0]=v[0]*v[0]; f[1]=v[0]*v[1]; f[2]=v[0]*v[2]; f[3]=v[0]*v[3];
            f[4]=v[0]*v[4]; f[5]=v[0]*v[5]; f[6]=v[1]*v[1]; f[7]=v[1]*v[2];
        } else if (quad == 1) {
            f[0]=v[1]*v[3]; f[1]=v[1]*v[4]; f[2]=v[1]*v[5]; f[3]=v[2]*v[2];
            f[4]=v[2]*v[3]; f[5]=v[2]*v[4]; f[6]=v[2]*v[5]; f[7]=v[3]*v[3];
        } else if (quad == 2) {
            f[0]=v[3]*v[4]; f[1]=v[3]*v[5]; f[2]=v[4]*v[4]; f[3]=v[4]*v[5];
            f[4]=v[5]*v[5]; f[5]=v[0];      f[6]=v[1];      f[7]=v[2];
        } else {
            f[0]=v[3]; f[1]=v[4]; f[2]=v[5]; f[3]=1.0f;
            f[4]=0.0f; f[5]=0.0f; f[6]=0.0f; f[7]=0.0f;
        }

        bf16x8 frag;
        #pragma unroll
        for (int j = 0; j < 8; j++) {
            unsigned short h = f32_to_bf16(f[j]);
            frag[j] = (split == 0) ? (short)h
                                   : (short)f32_to_bf16(f[j] - bf16_to_f32(h));
        }
        fragA[w][lane] = frag;
    }
    __syncthreads();

    bf16x8 Ah[4], Al[4];
    #pragma unroll
    for (int pt = 0; pt < 4; pt++) {
        Ah[pt] = fragA[pt][lane];
        Al[pt] = fragA[4 + pt][lane];
    }

    // ---- MFMA loop over this wave's 4 n-tiles ----
    const bf16x8* WhF = (const bf16x8*)Wh + (w * NTPW) * 64;
    const bf16x8* WlF = (const bf16x8*)Wl + (w * NTPW) * 64;

    float esum[4][4];
    #pragma unroll
    for (int pt = 0; pt < 4; pt++)
        #pragma unroll
        for (int r = 0; r < 4; r++) esum[pt][r] = 0.0f;

    #pragma unroll
    for (int t = 0; t < NTPW; t++) {
        bf16x8 bh = WhF[t * 64 + lane];
        bf16x8 bl = WlF[t * 64 + lane];
        #pragma unroll
        for (int pt = 0; pt < 4; pt++) {
            f32x4 c = {0.0f, 0.0f, 0.0f, 0.0f};
            c = __builtin_amdgcn_mfma_f32_16x16x32_bf16(Ah[pt], bh, c, 0, 0, 0);
            c = __builtin_amdgcn_mfma_f32_16x16x32_bf16(Al[pt], bh, c, 0, 0, 0);
            c = __builtin_amdgcn_mfma_f32_16x16x32_bf16(Ah[pt], bl, c, 0, 0, 0);
            #pragma unroll
            for (int r = 0; r < 4; r++)
                esum[pt][r] += __builtin_amdgcn_exp2f(c[r]);
        }
    }

    // ---- reduce over the 16 comp-lanes (DPP row_ror rotate-adds) ----
    #pragma unroll
    for (int pt = 0; pt < 4; pt++)
        #pragma unroll
        for (int r = 0; r < 4; r++)
            esum[pt][r] = row16_sum(esum[pt][r]);

    if (m15 == 0) {
        #pragma unroll
        for (int pt = 0; pt < 4; pt++)
            #pragma unroll
            for (int r = 0; r < 4; r++)
                partial[w][pt * 16 + quad * 4 + r] = esum[pt][r];
    }
    __syncthreads();

    if (tid < PTS) {
        float S = 0.0f;
        #pragma unroll
        for (int c = 0; c < NWAVE; c++) S += partial[c][tid];
        const float LN2 = 0.6931471805599453f;
        out[pbase + tid] = LN2 * __builtin_amdgcn_logf(S);  // v_log_f32 = log2
    }
}

extern "C" void kernel_launch(void* const* d_in, const int* in_sizes, int n_in,
                              void* d_out, int out_size, void* d_ws, size_t ws_size,
                              hipStream_t stream) {
    const float* x       = (const float*)d_in[0];  // [B, 6]
    const float* means   = (const float*)d_in[1];  // [K, 6]
    const float* covs    = (const float*)d_in[2];  // [K, 6, 6]
    const float* weights = (const float*)d_in[3];  // [K]
    float* out = (float*)d_out;                    // [B]

    unsigned short* Wh = (unsigned short*)d_ws;            // 32768 x bf16 (64 KB)
    unsigned short* Wl = Wh + 32768;                       // 32768 x bf16 (64 KB)

    gmm_precompute<<<KCOMP / 64, 64, 0, stream>>>(means, covs, weights, Wh, Wl);
    gmm_main<<<BPTS / PTS, 1024, 0, stream>>>(x, Wh, Wl, out);
}